// Round 12
// baseline (3456.947 us; speedup 1.0000x reference)
//
#include <hip/hip_runtime.h>

#define T_ 512
#define B_ 64
#define E_ 256
#define H_ 256

typedef __attribute__((ext_vector_type(8))) short short8_t;   // 8 bf16 (4 VGPRs)
typedef __attribute__((ext_vector_type(4))) float floatx4;
typedef __attribute__((ext_vector_type(4))) int intx4;        // 16 i8 (4 VGPRs)

__device__ __forceinline__ unsigned short f2bf(float f) {
  unsigned int u = __float_as_uint(f);
  u += 0x7FFFu + ((u >> 16) & 1u);           // RTNE
  return (unsigned short)(u >> 16);
}
__device__ __forceinline__ float bf2f(unsigned short s) {
  return __uint_as_float(((unsigned int)s) << 16);
}
__device__ __forceinline__ float fast_tanh(float x) {
  float e = __expf(-2.0f * x);
  return 2.0f / (1.0f + e) - 1.0f;
}

// ---------------------------------------------------------------------------
// Kernel 1: fused q/k projection (fp32; attention needs accuracy).
// ---------------------------------------------------------------------------
__global__ __launch_bounds__(256) void qk_kernel(
    const float* __restrict__ inp, const float* __restrict__ rot,
    const float* __restrict__ ent, float* __restrict__ qo, float* __restrict__ ko)
{
  __shared__ __align__(16) float As[16][136];
  __shared__ __align__(16) float B1[16][68];
  __shared__ __align__(16) float B2[16][68];
  const int tid = threadIdx.x;
  const int m0 = blockIdx.y * 128, n0 = blockIdx.x * 64;
  const int lk = tid & 15, lm = tid >> 4;
  const int ln = tid & 63, lkb = tid >> 6;
  const int tx = tid & 15, ty = tid >> 4;
  float acc1[8][4], acc2[8][4];
#pragma unroll
  for (int i = 0; i < 8; ++i)
#pragma unroll
    for (int j = 0; j < 4; ++j) { acc1[i][j] = 0.f; acc2[i][j] = 0.f; }

  for (int k0 = 0; k0 < 256; k0 += 16) {
    __syncthreads();
#pragma unroll
    for (int p = 0; p < 8; ++p) {
      int m = lm + p * 16;
      As[lk][m] = inp[(size_t)(m0 + m) * 256 + k0 + lk];
    }
#pragma unroll
    for (int p = 0; p < 4; ++p) {
      int kk = lkb + p * 4;
      B1[kk][ln] = rot[(size_t)(k0 + kk) * 256 + n0 + ln];
      B2[kk][ln] = ent[(size_t)(k0 + kk) * 256 + n0 + ln];
    }
    __syncthreads();
#pragma unroll
    for (int kk = 0; kk < 16; ++kk) {
      floatx4 a_lo = *(const floatx4*)&As[kk][ty * 8];
      floatx4 a_hi = *(const floatx4*)&As[kk][ty * 8 + 4];
      floatx4 b1v = *(const floatx4*)&B1[kk][tx * 4];
      floatx4 b2v = *(const floatx4*)&B2[kk][tx * 4];
#pragma unroll
      for (int i = 0; i < 4; ++i) {
        float alo = a_lo[i], ahi = a_hi[i];
#pragma unroll
        for (int j = 0; j < 4; ++j) {
          acc1[i][j]     += alo * b1v[j];
          acc1[i + 4][j] += ahi * b1v[j];
          acc2[i][j]     += alo * b2v[j];
          acc2[i + 4][j] += ahi * b2v[j];
        }
      }
    }
  }
#pragma unroll
  for (int i = 0; i < 8; ++i) {
    size_t row = (size_t)(m0 + ty * 8 + i);
    float4 v1 = make_float4(acc1[i][0], acc1[i][1], acc1[i][2], acc1[i][3]);
    float4 v2 = make_float4(acc2[i][0], acc2[i][1], acc2[i][2], acc2[i][3]);
    *(float4*)&qo[row * 256 + n0 + tx * 4] = v1;
    *(float4*)&ko[row * 256 + n0 + tx * 4] = v2;
  }
}

// ---------------------------------------------------------------------------
// Kernel 2: scores (NT, fp32), 128x128 tile, 8x8 acc/thread.
// ---------------------------------------------------------------------------
__global__ __launch_bounds__(256) void scores_kernel(
    const float* __restrict__ q, const float* __restrict__ k, float* __restrict__ S)
{
  __shared__ __align__(16) float As[16][136];
  __shared__ __align__(16) float Bs[16][136];
  const int tid = threadIdx.x;
  const int b = blockIdx.z;
  const int m0 = blockIdx.y * 128, n0 = blockIdx.x * 128;
  const int lk = tid & 15, lm = tid >> 4;
  const int tx = tid & 15, ty = tid >> 4;
  float acc[8][8];
#pragma unroll
  for (int i = 0; i < 8; ++i)
#pragma unroll
    for (int j = 0; j < 8; ++j) acc[i][j] = 0.f;

  const float* Ab = q + (size_t)b * 256;
  const float* Bb = k + (size_t)b * 256;
  for (int k0 = 0; k0 < 256; k0 += 16) {
    __syncthreads();
#pragma unroll
    for (int p = 0; p < 8; ++p) {
      int m = lm + p * 16;
      As[lk][m] = Ab[(size_t)(m0 + m) * 16384 + k0 + lk];
      Bs[lk][m] = Bb[(size_t)(n0 + m) * 16384 + k0 + lk];
    }
    __syncthreads();
#pragma unroll
    for (int kk = 0; kk < 16; ++kk) {
      floatx4 a_lo = *(const floatx4*)&As[kk][ty * 8];
      floatx4 a_hi = *(const floatx4*)&As[kk][ty * 8 + 4];
      floatx4 b_lo = *(const floatx4*)&Bs[kk][tx * 8];
      floatx4 b_hi = *(const floatx4*)&Bs[kk][tx * 8 + 4];
      float av[8], bv[8];
#pragma unroll
      for (int i = 0; i < 4; ++i) { av[i] = a_lo[i]; av[i + 4] = a_hi[i];
                                    bv[i] = b_lo[i]; bv[i + 4] = b_hi[i]; }
#pragma unroll
      for (int i = 0; i < 8; ++i)
#pragma unroll
        for (int j = 0; j < 8; ++j)
          acc[i][j] += av[i] * bv[j];
    }
  }
#pragma unroll
  for (int i = 0; i < 8; ++i) {
    size_t off = (size_t)b * 262144 + (size_t)(m0 + ty * 8 + i) * 512 + n0 + tx * 8;
    float4 v0 = make_float4(acc[i][0] * 0.0625f, acc[i][1] * 0.0625f,
                            acc[i][2] * 0.0625f, acc[i][3] * 0.0625f);
    float4 v1 = make_float4(acc[i][4] * 0.0625f, acc[i][5] * 0.0625f,
                            acc[i][6] * 0.0625f, acc[i][7] * 0.0625f);
    *(float4*)&S[off] = v0;
    *(float4*)&S[off + 4] = v1;
  }
}

// ---------------------------------------------------------------------------
// Kernel 3: in-place row softmax over 512 elements, 32768 rows.
// ---------------------------------------------------------------------------
__global__ __launch_bounds__(256) void softmax_kernel(float* __restrict__ S)
{
  float* p = S + (size_t)blockIdx.x * 512;
  const int tid = threadIdx.x;
  float x0 = p[tid], x1 = p[tid + 256];
  float m = fmaxf(x0, x1);
#pragma unroll
  for (int off = 32; off > 0; off >>= 1) m = fmaxf(m, __shfl_xor(m, off));
  __shared__ float red[8];
  const int wv = tid >> 6;
  if ((tid & 63) == 0) red[wv] = m;
  __syncthreads();
  m = fmaxf(fmaxf(red[0], red[1]), fmaxf(red[2], red[3]));
  float e0 = __expf(x0 - m);
  float e1 = __expf(x1 - m);
  float s = e0 + e1;
#pragma unroll
  for (int off = 32; off > 0; off >>= 1) s += __shfl_xor(s, off);
  if ((tid & 63) == 0) red[4 + wv] = s;
  __syncthreads();
  s = red[4] + red[5] + red[6] + red[7];
  float r = 1.0f / s;
  p[tid] = e0 * r;
  p[tid + 256] = e1 * r;
}

// ---------------------------------------------------------------------------
// Kernel 4: context (NN, fp32), 128x128 tile, 8x8 acc/thread.
// ---------------------------------------------------------------------------
__global__ __launch_bounds__(256) void context_kernel(
    const float* __restrict__ P, const float* __restrict__ inp, float* __restrict__ ctx)
{
  __shared__ __align__(16) float As[16][136];
  __shared__ __align__(16) float Bs[16][136];
  const int tid = threadIdx.x;
  const int b = blockIdx.z;
  const int m0 = blockIdx.y * 128, e0 = blockIdx.x * 128;
  const int lk = tid & 15, lm = tid >> 4;
  const int tx = tid & 15, ty = tid >> 4;
  const int bk = tid >> 7, be = tid & 127;
  float acc[8][8];
#pragma unroll
  for (int i = 0; i < 8; ++i)
#pragma unroll
    for (int j = 0; j < 8; ++j) acc[i][j] = 0.f;

  const float* Ab = P + (size_t)b * 262144;
  for (int k0 = 0; k0 < 512; k0 += 16) {
    __syncthreads();
#pragma unroll
    for (int p = 0; p < 8; ++p) {
      int m = lm + p * 16;
      As[lk][m] = Ab[(size_t)(m0 + m) * 512 + k0 + lk];
    }
#pragma unroll
    for (int p = 0; p < 8; ++p) {
      int kk = bk + p * 2;
      Bs[kk][be] = inp[(size_t)(k0 + kk) * 16384 + b * 256 + e0 + be];
    }
    __syncthreads();
#pragma unroll
    for (int kk = 0; kk < 16; ++kk) {
      floatx4 a_lo = *(const floatx4*)&As[kk][ty * 8];
      floatx4 a_hi = *(const floatx4*)&As[kk][ty * 8 + 4];
      floatx4 b_lo = *(const floatx4*)&Bs[kk][tx * 8];
      floatx4 b_hi = *(const floatx4*)&Bs[kk][tx * 8 + 4];
      float av[8], bv[8];
#pragma unroll
      for (int i = 0; i < 4; ++i) { av[i] = a_lo[i]; av[i + 4] = a_hi[i];
                                    bv[i] = b_lo[i]; bv[i + 4] = b_hi[i]; }
#pragma unroll
      for (int i = 0; i < 8; ++i)
#pragma unroll
        for (int j = 0; j < 8; ++j)
          acc[i][j] += av[i] * bv[j];
    }
  }
#pragma unroll
  for (int i = 0; i < 8; ++i) {
    size_t off = (size_t)(m0 + ty * 8 + i) * 16384 + (size_t)b * 256 + e0 + tx * 8;
    float4 v0 = make_float4(acc[i][0], acc[i][1], acc[i][2], acc[i][3]);
    float4 v1 = make_float4(acc[i][4], acc[i][5], acc[i][6], acc[i][7]);
    *(float4*)&ctx[off] = v0;
    *(float4*)&ctx[off + 4] = v1;
  }
}

// ---------------------------------------------------------------------------
// Kernel 5: cp[t,b,h] = bc[h] + sum_e ctx[t,b,e] Wc[e,h]   (fp32)
// ---------------------------------------------------------------------------
__global__ __launch_bounds__(256) void cp_kernel(
    const float* __restrict__ ctx, const float* __restrict__ Wc,
    const float* __restrict__ bc, float* __restrict__ cp)
{
  __shared__ __align__(16) float As[16][136];
  __shared__ __align__(16) float Bs[16][68];
  const int tid = threadIdx.x;
  const int m0 = blockIdx.y * 128, n0 = blockIdx.x * 64;
  const int lk = tid & 15, lm = tid >> 4;
  const int ln = tid & 63, lkb = tid >> 6;
  const int tx = tid & 15, ty = tid >> 4;
  float acc[8][4];
#pragma unroll
  for (int i = 0; i < 8; ++i)
#pragma unroll
    for (int j = 0; j < 4; ++j) acc[i][j] = 0.f;

  for (int k0 = 0; k0 < 256; k0 += 16) {
    __syncthreads();
#pragma unroll
    for (int p = 0; p < 8; ++p) {
      int m = lm + p * 16;
      As[lk][m] = ctx[(size_t)(m0 + m) * 256 + k0 + lk];
    }
#pragma unroll
    for (int p = 0; p < 4; ++p) {
      int kk = lkb + p * 4;
      Bs[kk][ln] = Wc[(size_t)(k0 + kk) * 256 + n0 + ln];
    }
    __syncthreads();
#pragma unroll
    for (int kk = 0; kk < 16; ++kk) {
      floatx4 a_lo = *(const floatx4*)&As[kk][ty * 8];
      floatx4 a_hi = *(const floatx4*)&As[kk][ty * 8 + 4];
      floatx4 bv = *(const floatx4*)&Bs[kk][tx * 4];
#pragma unroll
      for (int i = 0; i < 4; ++i) {
        float alo = a_lo[i], ahi = a_hi[i];
#pragma unroll
        for (int j = 0; j < 4; ++j) {
          acc[i][j]     += alo * bv[j];
          acc[i + 4][j] += ahi * bv[j];
        }
      }
    }
  }
  float b0 = bc[n0 + tx * 4 + 0], b1 = bc[n0 + tx * 4 + 1];
  float b2 = bc[n0 + tx * 4 + 2], b3 = bc[n0 + tx * 4 + 3];
#pragma unroll
  for (int i = 0; i < 8; ++i) {
    size_t row = (size_t)(m0 + ty * 8 + i);
    float4 v = make_float4(acc[i][0] + b0, acc[i][1] + b1, acc[i][2] + b2, acc[i][3] + b3);
    *(float4*)&cp[row * 256 + n0 + tx * 4] = v;
  }
}

// ---------------------------------------------------------------------------
// Kernel 6a: pack gate weights.  bf16 Wt[n][k] + int8 Wh fragments + scales.
// (byte-identical layout to round 11, which passed correctness)
// ---------------------------------------------------------------------------
__global__ __launch_bounds__(256) void pack_w(
    const float* __restrict__ Wf, const float* __restrict__ Wi,
    const float* __restrict__ Wu, const float* __restrict__ Wo,
    const float* __restrict__ bfv, const float* __restrict__ biv,
    const float* __restrict__ buv, const float* __restrict__ bov,
    unsigned short* __restrict__ Wt, float* __restrict__ bcat,
    signed char* __restrict__ Wq, float* __restrict__ wscale)
{
  const int n = blockIdx.x;
  const int g = n >> 8, h = n & 255;
  const float* W = (g == 0) ? Wf : (g == 1) ? Wi : (g == 2) ? Wu : Wo;
  const float* bb = (g == 0) ? bfv : (g == 1) ? biv : (g == 2) ? buv : bov;
  const int tid = threadIdx.x;
  for (int k = tid; k < 512; k += 256)
    Wt[(size_t)n * 512 + k] = f2bf(W[(size_t)k * 256 + h]);
  if (tid == 0) bcat[n] = bb[h];

  float v = W[(size_t)(256 + tid) * 256 + h];
  float a = fabsf(v);
#pragma unroll
  for (int off = 32; off > 0; off >>= 1) a = fmaxf(a, __shfl_xor(a, off));
  __shared__ float mx[4];
  if ((tid & 63) == 0) mx[tid >> 6] = a;
  __syncthreads();
  float m = fmaxf(fmaxf(mx[0], mx[1]), fmaxf(mx[2], mx[3]));
  float s = fmaxf(m, 1e-12f) * (1.0f / 127.0f);
  int qv = (int)rintf(v / s);
  qv = qv < -127 ? -127 : (qv > 127 ? 127 : qv);
  const int w = h >> 5, hi = (h >> 4) & 1, lm = h & 15;
  const int nt = g * 2 + hi;
  const int kc = tid >> 6, qd = (tid >> 4) & 3, bb2 = tid & 15;
  const int lane = qd * 16 + lm;
  Wq[(size_t)(((w * 8 + nt) * 4 + kc)) * 1024 + lane * 16 + bb2] = (signed char)qv;
  if (tid == 0) wscale[w * 128 + nt * 16 + lm] = s * (1.0f / 127.0f);
}

// ---------------------------------------------------------------------------
// Kernel 6b: pre[m][n'] via bf16 MFMA; n' = h*4+g gate-interleaved.
// ---------------------------------------------------------------------------
__global__ __launch_bounds__(256) void gemm_pre(
    const float* __restrict__ x, const float* __restrict__ cp,
    const unsigned short* __restrict__ Wt, const float* __restrict__ bcat,
    unsigned short* __restrict__ pre)
{
  __shared__ __align__(16) unsigned short As[64 * 40];
  __shared__ __align__(16) unsigned short Bs[64 * 40];
  const int tid = threadIdx.x;
  const int n0 = blockIdx.x * 64, m0 = blockIdx.y * 64;
  const int lane = tid & 63, wv = tid >> 6;
  const int lm = lane & 15, qd = lane >> 4;
  const int sr = tid >> 2, sk = (tid & 3) * 8;
  floatx4 acc[4] = {{0.f,0.f,0.f,0.f},{0.f,0.f,0.f,0.f},
                    {0.f,0.f,0.f,0.f},{0.f,0.f,0.f,0.f}};
  for (int k0 = 0; k0 < 512; k0 += 32) {
    const float* Asrc = (k0 < 256)
        ? (x  + (size_t)(m0 + sr) * 256 + k0 + sk)
        : (cp + (size_t)(m0 + sr) * 256 + (k0 - 256) + sk);
    float4 a0 = *(const float4*)Asrc;
    float4 a1 = *(const float4*)(Asrc + 4);
    short8_t av;
    av[0] = (short)f2bf(a0.x); av[1] = (short)f2bf(a0.y);
    av[2] = (short)f2bf(a0.z); av[3] = (short)f2bf(a0.w);
    av[4] = (short)f2bf(a1.x); av[5] = (short)f2bf(a1.y);
    av[6] = (short)f2bf(a1.z); av[7] = (short)f2bf(a1.w);
    short8_t bv = *(const short8_t*)&Wt[(size_t)(n0 + sr) * 512 + k0 + sk];
    *(short8_t*)&As[sr * 40 + sk] = av;
    *(short8_t*)&Bs[sr * 40 + sk] = bv;
    __syncthreads();
    short8_t af = *(const short8_t*)&As[(wv * 16 + lm) * 40 + qd * 8];
#pragma unroll
    for (int nt = 0; nt < 4; ++nt) {
      short8_t bf = *(const short8_t*)&Bs[(nt * 16 + lm) * 40 + qd * 8];
      acc[nt] = __builtin_amdgcn_mfma_f32_16x16x32_bf16(af, bf, acc[nt], 0, 0, 0);
    }
    __syncthreads();
  }
#pragma unroll
  for (int nt = 0; nt < 4; ++nt) {
    int col = n0 + nt * 16 + lm;
    float bb = bcat[col];
    int col2 = ((col & 255) << 2) | (col >> 8);
#pragma unroll
    for (int r = 0; r < 4; ++r) {
      int row = m0 + wv * 16 + qd * 4 + r;
      pre[(size_t)row * 1024 + col2] = f2bf(acc[nt][r] + bb);
    }
  }
}

// ---------------------------------------------------------------------------
// Kernel 7: LSTM scan — ZERO-EXCHANGE int8, 4-WAVE WGs (full 512-reg budget).
// 4 WGs x 256 threads (4 waves, 1/SIMD -> launch_bounds(256,1), r4-proven
// AGPR path); WG bg owns batch rows [bg*16,+16).  Wave w4 owns h-cols
// [w4*64,+64) x all 4 gates: 16 MFMA n-tiles (nt = g*4+cg2).
// Wh-i8: kc 0-1 in regs (128/thread, AGPR-backed), kc 2-3 in LDS (128 KB).
// Thread owns 4 rows x 4 cols, all 4 gates in-register -> no shfl.
// ONE barrier/step; no spin loops -> deadlock impossible.
// ---------------------------------------------------------------------------
__global__ __launch_bounds__(256, 1) void scan_kernel(
    const unsigned short* __restrict__ pre,   // [32768][1024], col = h*4+g
    const signed char* __restrict__ Wq,       // fragment-ordered i8 Wh
    const float* __restrict__ wscale,         // [1024] folded scales
    float* __restrict__ out)
{
  __shared__ __align__(16) signed char wlds[131072];     // 128 KiB kc 2-3 frags
  __shared__ __align__(16) signed char hq[2][16 * 272];  // 8.5 KiB h-i8 dbuf
  const int tid = threadIdx.x;
  const int bg = blockIdx.x;           // batch group 0..3 (16 rows)
  const int lane = tid & 63;
  const int w4 = tid >> 6;             // wave 0..3 -> h-cols [w4*64, +64)
  const int qd = lane >> 4;
  const int lm = lane & 15;

  // zero both h buffers: 2*16*272 = 8704 B = 1088 u64
  {
    unsigned long long* z = (unsigned long long*)hq;
    for (int i = tid; i < 1088; i += 256) z[i] = 0ull;
  }

  // Wh fragments: nt = g*4+cg2; map to pack_w's (w_old, nt_old) coords.
  // kc 0,1 -> regs (wreg[nt*2+kc]); kc 2,3 -> LDS slot nt*2+(kc-2).
  intx4 wreg[32];
  float ws[16];
#pragma unroll
  for (int nt = 0; nt < 16; ++nt) {
    const int g = nt >> 2, cg2 = nt & 3;
    const int w_old = w4 * 2 + (cg2 >> 1);
    const int nt_old = g * 2 + (cg2 & 1);
    ws[nt] = wscale[w_old * 128 + nt_old * 16 + lm];
#pragma unroll
    for (int kc = 0; kc < 4; ++kc) {
      intx4 v = *(const intx4*)&Wq[(size_t)(((w_old * 8 + nt_old) * 4 + kc)) * 1024
                                   + lane * 16];
      if (kc < 2) wreg[nt * 2 + kc] = v;
      else *(intx4*)&wlds[w4 * 32768 + (nt * 2 + (kc - 2)) * 1024 + lane * 16] = v;
    }
  }

  const unsigned long long* pq = (const unsigned long long*)pre;
  const int row0 = bg * 16 + qd * 4;            // this thread's 4 batch rows
  unsigned long long pcur[4][4], pnext[4][4];   // [cg2][r]
#pragma unroll
  for (int cg2 = 0; cg2 < 4; ++cg2) {
    const int col = w4 * 64 + cg2 * 16 + lm;
#pragma unroll
    for (int r = 0; r < 4; ++r)
      pcur[cg2][r] = pq[(size_t)(row0 + r) * 256 + col];
  }
  float cst[4][4];
#pragma unroll
  for (int cg2 = 0; cg2 < 4; ++cg2)
#pragma unroll
    for (int r = 0; r < 4; ++r) cst[cg2][r] = 0.f;

  __syncthreads();   // wlds + hq zeros visible

#pragma unroll 1
  for (int t = 0; t < 512; ++t) {
    const signed char* hR = hq[t & 1];
    signed char* hW = hq[(t + 1) & 1];

    // prefetch pre(t+1) (consumed next step; a full step of slack)
    if (t < 511) {
      size_t base = (size_t)((t + 1) * 64 + row0) * 256;
#pragma unroll
      for (int cg2 = 0; cg2 < 4; ++cg2) {
        const int col = w4 * 64 + cg2 * 16 + lm;
#pragma unroll
        for (int r = 0; r < 4; ++r)
          pnext[cg2][r] = pq[base + (size_t)r * 256 + col];
      }
    }

    // gates(16 x 256 n' per wave) = hq(16x256 i8) @ Wh-i8  (i32 accum)
    intx4 acc[16];
#pragma unroll
    for (int nt = 0; nt < 16; ++nt) acc[nt] = (intx4){0, 0, 0, 0};
#pragma unroll
    for (int kc = 0; kc < 4; ++kc) {
      intx4 av = *(const intx4*)&hR[lm * 272 + kc * 64 + qd * 16];
#pragma unroll
      for (int nt = 0; nt < 16; ++nt) {
        intx4 bv;
        if (kc < 2) bv = wreg[nt * 2 + kc];
        else bv = *(const intx4*)&wlds[w4 * 32768 + (nt * 2 + (kc - 2)) * 1024 + lane * 16];
        acc[nt] = __builtin_amdgcn_mfma_i32_16x16x64_i8(av, bv, acc[nt], 0, 0, 0);
      }
    }

    // epilogue: 4 cols x 4 rows, all 4 gates in-thread
#pragma unroll
    for (int cg2 = 0; cg2 < 4; ++cg2) {
      const int col = w4 * 64 + cg2 * 16 + lm;
#pragma unroll
      for (int r = 0; r < 4; ++r) {
        unsigned long long pv = pcur[cg2][r];
        float xf = (float)acc[cg2][r]      * ws[cg2]      + bf2f((unsigned short)pv);
        float xi = (float)acc[4 + cg2][r]  * ws[4 + cg2]  + bf2f((unsigned short)(pv >> 16));
        float xu = (float)acc[8 + cg2][r]  * ws[8 + cg2]  + bf2f((unsigned short)(pv >> 32));
        float xo = (float)acc[12 + cg2][r] * ws[12 + cg2] + bf2f((unsigned short)(pv >> 48));
        float fg = 1.0f / (1.0f + __expf(-xf));
        float ig = 1.0f / (1.0f + __expf(-xi));
        float gg = fast_tanh(xu);
        float og = 1.0f / (1.0f + __expf(-xo));
        float cc = fg * cst[cg2][r] + ig * gg;
        cst[cg2][r] = cc;
        float hh = og * fast_tanh(cc);
        int hv = (int)rintf(hh * 127.0f);
        hv = hv < -127 ? -127 : (hv > 127 ? 127 : hv);
        hW[(qd * 4 + r) * 272 + col] = (signed char)hv;
        out[(size_t)t * 16384 + (size_t)(row0 + r) * 256 + col] = hh;
        if (t == 511) {
          const size_t hoff = (size_t)512 * 16384 + (size_t)(row0 + r) * 256 + col;
          out[hoff] = hh;              // hx
          out[hoff + 16384] = cc;      // cx
        }
      }
    }
#pragma unroll
    for (int cg2 = 0; cg2 < 4; ++cg2)
#pragma unroll
      for (int r = 0; r < 4; ++r) pcur[cg2][r] = pnext[cg2][r];
    __syncthreads();   // hW complete before next step's MFMA reads it
  }
}

// ---------------------------------------------------------------------------
extern "C" void kernel_launch(void* const* d_in, const int* in_sizes, int n_in,
                              void* d_out, int out_size, void* d_ws, size_t ws_size,
                              hipStream_t stream)
{
  const float* inputs = (const float*)d_in[0];
  const float* rot = (const float*)d_in[1];
  const float* ent = (const float*)d_in[2];
  const float* Wf = (const float*)d_in[3];
  const float* bf_ = (const float*)d_in[4];
  const float* Wi = (const float*)d_in[5];
  const float* bi_ = (const float*)d_in[6];
  const float* Wu = (const float*)d_in[7];
  const float* bu_ = (const float*)d_in[8];
  const float* Wo = (const float*)d_in[9];
  const float* bo_ = (const float*)d_in[10];
  const float* Wc = (const float*)d_in[11];
  const float* bc_ = (const float*)d_in[12];
  float* out = (float*)d_out;

  char* ws = (char*)d_ws;
  float* q  = (float*)(ws);                                   // 32 MiB [T,B,E]
  float* kb = (float*)(ws + (size_t)32 * 1024 * 1024);        // 32 MiB [T,B,E]
  float* S  = (float*)(ws + (size_t)64 * 1024 * 1024);        // 64 MiB [B,T,T]
  unsigned short* pre = (unsigned short*)S;                   // aliases S (dead)
  float* ctx = q;                                             // aliases q (dead)
  float* cp  = kb;                                            // aliases k (dead)
  // q region dead after cp_kernel -> packed weights live there
  unsigned short* Wcat = (unsigned short*)ws;                 // 1 MiB [1024][512]
  float* bcat = (float*)(ws + (size_t)1048576);               // 4 KiB
  signed char* Wq = (signed char*)(ws + (size_t)2 * 1024 * 1024);  // 256 KiB
  float* wscale = (float*)(ws + (size_t)2 * 1024 * 1024 + 262144); // 4 KiB

  qk_kernel<<<dim3(4, 256), 256, 0, stream>>>(inputs, rot, ent, q, kb);
  scores_kernel<<<dim3(4, 4, 64), 256, 0, stream>>>(q, kb, S);
  softmax_kernel<<<dim3(32768), 256, 0, stream>>>(S);
  context_kernel<<<dim3(2, 4, 64), 256, 0, stream>>>(S, inputs, ctx);
  cp_kernel<<<dim3(4, 256), 256, 0, stream>>>(ctx, Wc, bc_, cp);
  pack_w<<<dim3(1024), 256, 0, stream>>>(Wf, Wi, Wu, Wo, bf_, bi_, bu_, bo_,
                                         Wcat, bcat, Wq, wscale);
  gemm_pre<<<dim3(16, 512), 256, 0, stream>>>(inputs, cp, Wcat, bcat, pre);
  scan_kernel<<<dim3(4), 256, 0, stream>>>(pre, Wq, wscale, out);
}

// Round 13
// 1828.667 us; speedup vs baseline: 1.8904x; 1.8904x over previous
//
#include <hip/hip_runtime.h>

#define T_ 512
#define B_ 64
#define E_ 256
#define H_ 256

typedef __attribute__((ext_vector_type(8))) short short8_t;   // 8 bf16 (4 VGPRs)
typedef __attribute__((ext_vector_type(4))) float floatx4;

__device__ __forceinline__ unsigned short f2bf(float f) {
  unsigned int u = __float_as_uint(f);
  u += 0x7FFFu + ((u >> 16) & 1u);           // RTNE
  return (unsigned short)(u >> 16);
}
__device__ __forceinline__ float bf2f(unsigned short s) {
  return __uint_as_float(((unsigned int)s) << 16);
}
__device__ __forceinline__ float fast_tanh(float x) {
  // tanh(x) = 2/(1+e^{-2x}) - 1 ; exact at saturation, ~1e-7 abs err near 0
  float e = __expf(-2.0f * x);
  return 2.0f / (1.0f + e) - 1.0f;
}

// ---------------------------------------------------------------------------
// Kernel 1: fused q/k projection.  q[t,b,f] = sum_e inp[t,b,e] rot[e,f]
// M = T*B = 32768 flat rows, K=256, N=256.  fp32 (attention needs accuracy).
// ---------------------------------------------------------------------------
__global__ __launch_bounds__(256) void qk_kernel(
    const float* __restrict__ inp, const float* __restrict__ rot,
    const float* __restrict__ ent, float* __restrict__ qo, float* __restrict__ ko)
{
  __shared__ __align__(16) float As[16][136];
  __shared__ __align__(16) float B1[16][68];
  __shared__ __align__(16) float B2[16][68];
  const int tid = threadIdx.x;
  const int m0 = blockIdx.y * 128, n0 = blockIdx.x * 64;
  const int lk = tid & 15, lm = tid >> 4;
  const int ln = tid & 63, lkb = tid >> 6;
  const int tx = tid & 15, ty = tid >> 4;
  float acc1[8][4], acc2[8][4];
#pragma unroll
  for (int i = 0; i < 8; ++i)
#pragma unroll
    for (int j = 0; j < 4; ++j) { acc1[i][j] = 0.f; acc2[i][j] = 0.f; }

  for (int k0 = 0; k0 < 256; k0 += 16) {
    __syncthreads();
#pragma unroll
    for (int p = 0; p < 8; ++p) {
      int m = lm + p * 16;
      As[lk][m] = inp[(size_t)(m0 + m) * 256 + k0 + lk];
    }
#pragma unroll
    for (int p = 0; p < 4; ++p) {
      int kk = lkb + p * 4;
      B1[kk][ln] = rot[(size_t)(k0 + kk) * 256 + n0 + ln];
      B2[kk][ln] = ent[(size_t)(k0 + kk) * 256 + n0 + ln];
    }
    __syncthreads();
#pragma unroll
    for (int kk = 0; kk < 16; ++kk) {
      floatx4 a_lo = *(const floatx4*)&As[kk][ty * 8];
      floatx4 a_hi = *(const floatx4*)&As[kk][ty * 8 + 4];
      floatx4 b1v = *(const floatx4*)&B1[kk][tx * 4];
      floatx4 b2v = *(const floatx4*)&B2[kk][tx * 4];
#pragma unroll
      for (int i = 0; i < 4; ++i) {
        float alo = a_lo[i], ahi = a_hi[i];
#pragma unroll
        for (int j = 0; j < 4; ++j) {
          acc1[i][j]     += alo * b1v[j];
          acc1[i + 4][j] += ahi * b1v[j];
          acc2[i][j]     += alo * b2v[j];
          acc2[i + 4][j] += ahi * b2v[j];
        }
      }
    }
  }
#pragma unroll
  for (int i = 0; i < 8; ++i) {
    size_t row = (size_t)(m0 + ty * 8 + i);
    float4 v1 = make_float4(acc1[i][0], acc1[i][1], acc1[i][2], acc1[i][3]);
    float4 v2 = make_float4(acc2[i][0], acc2[i][1], acc2[i][2], acc2[i][3]);
    *(float4*)&qo[row * 256 + n0 + tx * 4] = v1;
    *(float4*)&ko[row * 256 + n0 + tx * 4] = v2;
  }
}

// ---------------------------------------------------------------------------
// Kernel 2: scores S[b,t,s] = (q[t,b,:] . k[s,b,:]) / 16 — SPLIT-BF16 MFMA.
// a = hi + lo (hi=bf16(a), lo=bf16(a-hi)); a.b ~ hi.hi + hi.lo + lo.hi via a
// single bf16 MFMA GEMM with K'=768:
//   chunks c 0-7: A=hi(q), B=hi(k); 8-15: A=hi(q), B=lo(k); 16-23: A=lo(q), B=hi(k)
// 64x64 tile, 4 waves (gemm_pre skeleton).  Rel err ~3e-5 -> logit err ~0.008.
// ---------------------------------------------------------------------------
__global__ __launch_bounds__(256) void scores_kernel(
    const float* __restrict__ q, const float* __restrict__ k, float* __restrict__ S)
{
  __shared__ __align__(16) unsigned short As[64 * 40];
  __shared__ __align__(16) unsigned short Bs[64 * 40];
  const int tid = threadIdx.x;
  const int b = blockIdx.z;
  const int n0 = blockIdx.x * 64, m0 = blockIdx.y * 64;
  const int lane = tid & 63, wv = tid >> 6;
  const int lm = lane & 15, qd = lane >> 4;
  const int sr = tid >> 2, sk = (tid & 3) * 8;
  floatx4 acc[4] = {{0.f,0.f,0.f,0.f},{0.f,0.f,0.f,0.f},
                    {0.f,0.f,0.f,0.f},{0.f,0.f,0.f,0.f}};
  for (int c = 0; c < 24; ++c) {
    const int k0 = c * 32;
    const int off = (k0 & 255) + sk;              // source col within fp32 array
    const bool aLo = (c >= 16);
    const bool bLo = (c >= 8) && (c < 16);
    const float* Ap = q + ((size_t)(m0 + sr) * 64 + b) * 256 + off;
    const float* Bp = k + ((size_t)(n0 + sr) * 64 + b) * 256 + off;
    float4 a0 = *(const float4*)Ap;  float4 a1 = *(const float4*)(Ap + 4);
    float4 b0 = *(const float4*)Bp;  float4 b1 = *(const float4*)(Bp + 4);
    float af_[8] = {a0.x,a0.y,a0.z,a0.w,a1.x,a1.y,a1.z,a1.w};
    float bf_[8] = {b0.x,b0.y,b0.z,b0.w,b1.x,b1.y,b1.z,b1.w};
    short8_t av, bv;
#pragma unroll
    for (int i = 0; i < 8; ++i) {
      unsigned short ha = f2bf(af_[i]);
      av[i] = aLo ? (short)f2bf(af_[i] - bf2f(ha)) : (short)ha;
      unsigned short hb = f2bf(bf_[i]);
      bv[i] = bLo ? (short)f2bf(bf_[i] - bf2f(hb)) : (short)hb;
    }
    *(short8_t*)&As[sr * 40 + sk] = av;
    *(short8_t*)&Bs[sr * 40 + sk] = bv;
    __syncthreads();
    short8_t af = *(const short8_t*)&As[(wv * 16 + lm) * 40 + qd * 8];
#pragma unroll
    for (int nt = 0; nt < 4; ++nt) {
      short8_t bf = *(const short8_t*)&Bs[(nt * 16 + lm) * 40 + qd * 8];
      acc[nt] = __builtin_amdgcn_mfma_f32_16x16x32_bf16(af, bf, acc[nt], 0, 0, 0);
    }
    __syncthreads();
  }
#pragma unroll
  for (int nt = 0; nt < 4; ++nt) {
    const int col = n0 + nt * 16 + lm;
#pragma unroll
    for (int r = 0; r < 4; ++r) {
      const int row = m0 + wv * 16 + qd * 4 + r;
      S[(size_t)b * 262144 + (size_t)row * 512 + col] = acc[nt][r] * 0.0625f;
    }
  }
}

// ---------------------------------------------------------------------------
// Kernel 3: in-place row softmax over 512 elements, 32768 rows.
// ---------------------------------------------------------------------------
__global__ __launch_bounds__(256) void softmax_kernel(float* __restrict__ S)
{
  float* p = S + (size_t)blockIdx.x * 512;
  const int tid = threadIdx.x;
  float x0 = p[tid], x1 = p[tid + 256];
  float m = fmaxf(x0, x1);
#pragma unroll
  for (int off = 32; off > 0; off >>= 1) m = fmaxf(m, __shfl_xor(m, off));
  __shared__ float red[8];
  const int wv = tid >> 6;
  if ((tid & 63) == 0) red[wv] = m;
  __syncthreads();
  m = fmaxf(fmaxf(red[0], red[1]), fmaxf(red[2], red[3]));
  float e0 = __expf(x0 - m);
  float e1 = __expf(x1 - m);
  float s = e0 + e1;
#pragma unroll
  for (int off = 32; off > 0; off >>= 1) s += __shfl_xor(s, off);
  if ((tid & 63) == 0) red[4 + wv] = s;
  __syncthreads();
  s = red[4] + red[5] + red[6] + red[7];
  float r = 1.0f / s;
  p[tid] = e0 * r;
  p[tid + 256] = e1 * r;
}

// ---------------------------------------------------------------------------
// Kernel 4: context[t,b,e] = sum_s P[b,t,s] inp[s,b,e] — SPLIT-BF16 MFMA.
// K'=1536: c 0-15 P_hi.inp_hi; 16-31 P_hi.inp_lo; 32-47 P_lo.inp_hi.
// B (inp) staged TRANSPOSED to [e][s] on the fly.  64x64 tile, 4 waves.
// ---------------------------------------------------------------------------
__global__ __launch_bounds__(256) void context_kernel(
    const float* __restrict__ P, const float* __restrict__ inp, float* __restrict__ ctx)
{
  __shared__ __align__(16) unsigned short As[64 * 40];
  __shared__ __align__(16) unsigned short Bs[64 * 40];
  const int tid = threadIdx.x;
  const int b = blockIdx.z;
  const int e0 = blockIdx.x * 64, m0 = blockIdx.y * 64;
  const int lane = tid & 63, wv = tid >> 6;
  const int lm = lane & 15, qd = lane >> 4;
  const int sr = tid >> 2, sk = (tid & 3) * 8;     // A staging coords
  const int bkk = tid >> 3, be8 = (tid & 7) * 8;   // B staging: kk 0..31, e-oct
  floatx4 acc[4] = {{0.f,0.f,0.f,0.f},{0.f,0.f,0.f,0.f},
                    {0.f,0.f,0.f,0.f},{0.f,0.f,0.f,0.f}};
  for (int c = 0; c < 48; ++c) {
    const int k0 = c * 32;
    const int soff = k0 & 511;                     // source s within [0,512)
    const bool aLo = (c >= 32);
    const bool bLo = (c >= 16) && (c < 32);
    // A: P rows t = m0+sr, cols soff+sk
    const float* Ap = P + (size_t)b * 262144 + (size_t)(m0 + sr) * 512 + soff + sk;
    float4 a0 = *(const float4*)Ap;  float4 a1 = *(const float4*)(Ap + 4);
    float af_[8] = {a0.x,a0.y,a0.z,a0.w,a1.x,a1.y,a1.z,a1.w};
    short8_t av;
#pragma unroll
    for (int i = 0; i < 8; ++i) {
      unsigned short ha = f2bf(af_[i]);
      av[i] = aLo ? (short)f2bf(af_[i] - bf2f(ha)) : (short)ha;
    }
    // B: inp[s = soff+bkk][b*256 + e0+be8 .. +7], transposed into Bs[e][kk]
    const float* Bp = inp + (size_t)(soff + bkk) * 16384 + (size_t)b * 256 + e0 + be8;
    float4 b0 = *(const float4*)Bp;  float4 b1 = *(const float4*)(Bp + 4);
    float bf_[8] = {b0.x,b0.y,b0.z,b0.w,b1.x,b1.y,b1.z,b1.w};
    unsigned short bq[8];
#pragma unroll
    for (int i = 0; i < 8; ++i) {
      unsigned short hb = f2bf(bf_[i]);
      bq[i] = bLo ? f2bf(bf_[i] - bf2f(hb)) : hb;
    }
    *(short8_t*)&As[sr * 40 + sk] = av;
#pragma unroll
    for (int i = 0; i < 8; ++i)
      Bs[(be8 + i) * 40 + bkk] = bq[i];
    __syncthreads();
    short8_t af = *(const short8_t*)&As[(wv * 16 + lm) * 40 + qd * 8];
#pragma unroll
    for (int nt = 0; nt < 4; ++nt) {
      short8_t bf = *(const short8_t*)&Bs[(nt * 16 + lm) * 40 + qd * 8];
      acc[nt] = __builtin_amdgcn_mfma_f32_16x16x32_bf16(af, bf, acc[nt], 0, 0, 0);
    }
    __syncthreads();
  }
#pragma unroll
  for (int nt = 0; nt < 4; ++nt) {
    const int col = e0 + nt * 16 + lm;
#pragma unroll
    for (int r = 0; r < 4; ++r) {
      const int row = m0 + wv * 16 + qd * 4 + r;   // t index
      ctx[(size_t)row * 16384 + (size_t)b * 256 + col] = acc[nt][r];
    }
  }
}

// ---------------------------------------------------------------------------
// Kernel 5: cp[t,b,h] = bc[h] + sum_e ctx[t,b,e] Wc[e,h]   (fp32)
// ---------------------------------------------------------------------------
__global__ __launch_bounds__(256) void cp_kernel(
    const float* __restrict__ ctx, const float* __restrict__ Wc,
    const float* __restrict__ bc, float* __restrict__ cp)
{
  __shared__ __align__(16) float As[16][136];
  __shared__ __align__(16) float Bs[16][68];
  const int tid = threadIdx.x;
  const int m0 = blockIdx.y * 128, n0 = blockIdx.x * 64;
  const int lk = tid & 15, lm = tid >> 4;
  const int ln = tid & 63, lkb = tid >> 6;
  const int tx = tid & 15, ty = tid >> 4;
  float acc[8][4];
#pragma unroll
  for (int i = 0; i < 8; ++i)
#pragma unroll
    for (int j = 0; j < 4; ++j) acc[i][j] = 0.f;

  for (int k0 = 0; k0 < 256; k0 += 16) {
    __syncthreads();
#pragma unroll
    for (int p = 0; p < 8; ++p) {
      int m = lm + p * 16;
      As[lk][m] = ctx[(size_t)(m0 + m) * 256 + k0 + lk];
    }
#pragma unroll
    for (int p = 0; p < 4; ++p) {
      int kk = lkb + p * 4;
      Bs[kk][ln] = Wc[(size_t)(k0 + kk) * 256 + n0 + ln];
    }
    __syncthreads();
#pragma unroll
    for (int kk = 0; kk < 16; ++kk) {
      floatx4 a_lo = *(const floatx4*)&As[kk][ty * 8];
      floatx4 a_hi = *(const floatx4*)&As[kk][ty * 8 + 4];
      floatx4 bv = *(const floatx4*)&Bs[kk][tx * 4];
#pragma unroll
      for (int i = 0; i < 4; ++i) {
        float alo = a_lo[i], ahi = a_hi[i];
#pragma unroll
        for (int j = 0; j < 4; ++j) {
          acc[i][j]     += alo * bv[j];
          acc[i + 4][j] += ahi * bv[j];
        }
      }
    }
  }
  float b0 = bc[n0 + tx * 4 + 0], b1 = bc[n0 + tx * 4 + 1];
  float b2 = bc[n0 + tx * 4 + 2], b3 = bc[n0 + tx * 4 + 3];
#pragma unroll
  for (int i = 0; i < 8; ++i) {
    size_t row = (size_t)(m0 + ty * 8 + i);
    float4 v = make_float4(acc[i][0] + b0, acc[i][1] + b1, acc[i][2] + b2, acc[i][3] + b3);
    *(float4*)&cp[row * 256 + n0 + tx * 4] = v;
  }
}

// ---------------------------------------------------------------------------
// Kernel 6a: pack gate weights transposed to bf16.  Wt[n][k], n = g*256+h,
// k in [0,512): Wt[n*512+k] = W_g[k][h].  Also bcat[n] = b_g[h].
// ---------------------------------------------------------------------------
__global__ __launch_bounds__(256) void pack_w(
    const float* __restrict__ Wf, const float* __restrict__ Wi,
    const float* __restrict__ Wu, const float* __restrict__ Wo,
    const float* __restrict__ bfv, const float* __restrict__ biv,
    const float* __restrict__ buv, const float* __restrict__ bov,
    unsigned short* __restrict__ Wt, float* __restrict__ bcat)
{
  const int n = blockIdx.x;
  const int g = n >> 8, h = n & 255;
  const float* W = (g == 0) ? Wf : (g == 1) ? Wi : (g == 2) ? Wu : Wo;
  const float* bb = (g == 0) ? bfv : (g == 1) ? biv : (g == 2) ? buv : bov;
  for (int k = threadIdx.x; k < 512; k += 256)
    Wt[(size_t)n * 512 + k] = f2bf(W[(size_t)k * 256 + h]);
  if (threadIdx.x == 0) bcat[n] = bb[h];
}

// ---------------------------------------------------------------------------
// Kernel 6b: pre[m][n'] = bcat[n] + sum_k A[m][k] Wt[n][k]  via bf16 MFMA.
// A = [x | cp] (fp32 sources, converted to bf16 in staging), M=32768, K=512,
// N=1024.  64x64 tile, 4 waves.  OUTPUT gate-interleaved n' = h*4 + g.
// ---------------------------------------------------------------------------
__global__ __launch_bounds__(256) void gemm_pre(
    const float* __restrict__ x, const float* __restrict__ cp,
    const unsigned short* __restrict__ Wt, const float* __restrict__ bcat,
    unsigned short* __restrict__ pre)
{
  __shared__ __align__(16) unsigned short As[64 * 40];
  __shared__ __align__(16) unsigned short Bs[64 * 40];
  const int tid = threadIdx.x;
  const int n0 = blockIdx.x * 64, m0 = blockIdx.y * 64;
  const int lane = tid & 63, wv = tid >> 6;
  const int lm = lane & 15, qd = lane >> 4;
  const int sr = tid >> 2, sk = (tid & 3) * 8;
  floatx4 acc[4] = {{0.f,0.f,0.f,0.f},{0.f,0.f,0.f,0.f},
                    {0.f,0.f,0.f,0.f},{0.f,0.f,0.f,0.f}};
  for (int k0 = 0; k0 < 512; k0 += 32) {
    const float* Asrc = (k0 < 256)
        ? (x  + (size_t)(m0 + sr) * 256 + k0 + sk)
        : (cp + (size_t)(m0 + sr) * 256 + (k0 - 256) + sk);
    float4 a0 = *(const float4*)Asrc;
    float4 a1 = *(const float4*)(Asrc + 4);
    short8_t av;
    av[0] = (short)f2bf(a0.x); av[1] = (short)f2bf(a0.y);
    av[2] = (short)f2bf(a0.z); av[3] = (short)f2bf(a0.w);
    av[4] = (short)f2bf(a1.x); av[5] = (short)f2bf(a1.y);
    av[6] = (short)f2bf(a1.z); av[7] = (short)f2bf(a1.w);
    short8_t bv = *(const short8_t*)&Wt[(size_t)(n0 + sr) * 512 + k0 + sk];
    *(short8_t*)&As[sr * 40 + sk] = av;
    *(short8_t*)&Bs[sr * 40 + sk] = bv;
    __syncthreads();
    short8_t af = *(const short8_t*)&As[(wv * 16 + lm) * 40 + qd * 8];
#pragma unroll
    for (int nt = 0; nt < 4; ++nt) {
      short8_t bf = *(const short8_t*)&Bs[(nt * 16 + lm) * 40 + qd * 8];
      acc[nt] = __builtin_amdgcn_mfma_f32_16x16x32_bf16(af, bf, acc[nt], 0, 0, 0);
    }
    __syncthreads();
  }
#pragma unroll
  for (int nt = 0; nt < 4; ++nt) {
    int col = n0 + nt * 16 + lm;
    float bb = bcat[col];
    int col2 = ((col & 255) << 2) | (col >> 8);   // gate-interleaved
#pragma unroll
    for (int r = 0; r < 4; ++r) {
      int row = m0 + wv * 16 + qd * 4 + r;
      pre[(size_t)row * 1024 + col2] = f2bf(acc[nt][r] + bb);
    }
  }
}

// ---------------------------------------------------------------------------
// Kernel 7: persistent LSTM scan — round-4 winner, VERBATIM (1092 us).
// 16 WGs = 4 batch-groups x 4 h-blocks.  Wh in VGPRs; write-once NaN-sentinel
// data-polled exchange; hl double-buffered; one barrier/step.
// ---------------------------------------------------------------------------
__global__ __launch_bounds__(256, 1) void scan_kernel(
    const unsigned short* __restrict__ pre,   // [32768][1024], col = h*4+g
    const unsigned short* __restrict__ Wt,    // [1024][512],  n = g*256+h
    float* __restrict__ out, unsigned long long* __restrict__ hxT)
{
  __shared__ __align__(16) unsigned short hl[2][16 * 264];  // h double-buffer
  const int tid = threadIdx.x;
  const int bg = blockIdx.x >> 2;      // batch group 0..3 (16 rows)
  const int cg = blockIdx.x & 3;       // h-block 0..3 (64 cols)
  const int lane = tid & 63;
  const int w = tid >> 6;              // wave 0..3 -> cols [w*16, w*16+16)
  const int qd = lane >> 4;
  const int lh = lane & 15;

  {
    unsigned long long* z = (unsigned long long*)hl;
    for (int i = tid; i < 2112; i += 256) z[i] = 0ull;
  }

  short8_t wreg[4][8];
#pragma unroll
  for (int g = 0; g < 4; ++g)
#pragma unroll
    for (int kc = 0; kc < 8; ++kc)
      wreg[g][kc] = *(const short8_t*)&Wt[(size_t)(g * 256 + cg * 64 + w * 16 + lh) * 512
                                          + 256 + kc * 32 + qd * 8];

  const unsigned long long* pq = (const unsigned long long*)pre;
  const int orow0 = bg * 16 + qd * 4;
  const int hcol = cg * 64 + w * 16 + lh;
  unsigned long long pcur[4], pnext[4];
#pragma unroll
  for (int r = 0; r < 4; ++r)
    pcur[r] = pq[(size_t)(orow0 + r) * 256 + hcol];

  float cst[4] = {0.f, 0.f, 0.f, 0.f};
  const int cg1 = (cg + 1) & 3, cg2 = (cg + 2) & 3, cg3 = (cg + 3) & 3;
  const int prow = tid >> 4, pcolq = tid & 15;

  __syncthreads();

#pragma unroll 1
  for (int t = 0; t < 512; ++t) {
    unsigned long long* hlqR = (unsigned long long*)hl[t & 1];
    unsigned long long* hlqW = (unsigned long long*)hl[(t + 1) & 1];

    if (t > 0) {
      const unsigned long long* sbase = hxT + (size_t)((t - 1) * 4 + bg) * 1024;
      const unsigned long long* s0 = sbase + (size_t)cg1 * 256;
      const unsigned long long* s1 = sbase + (size_t)cg2 * 256;
      const unsigned long long* s2 = sbase + (size_t)cg3 * 256;
      unsigned long long d0, d1, d2;
      bool ok;
      do {
        d0 = __hip_atomic_load(&s0[tid], __ATOMIC_RELAXED, __HIP_MEMORY_SCOPE_AGENT);
        d1 = __hip_atomic_load(&s1[tid], __ATOMIC_RELAXED, __HIP_MEMORY_SCOPE_AGENT);
        d2 = __hip_atomic_load(&s2[tid], __ATOMIC_RELAXED, __HIP_MEMORY_SCOPE_AGENT);
        ok = ((unsigned int)d0 != 0xFFFFFFFFu) && ((unsigned int)(d0 >> 32) != 0xFFFFFFFFu)
          && ((unsigned int)d1 != 0xFFFFFFFFu) && ((unsigned int)(d1 >> 32) != 0xFFFFFFFFu)
          && ((unsigned int)d2 != 0xFFFFFFFFu) && ((unsigned int)(d2 >> 32) != 0xFFFFFFFFu);
      } while (!__all((int)ok));
      hlqR[prow * 66 + cg1 * 16 + pcolq] = d0;
      hlqR[prow * 66 + cg2 * 16 + pcolq] = d1;
      hlqR[prow * 66 + cg3 * 16 + pcolq] = d2;
    }

    if (t < 511) {
      size_t base = (size_t)((t + 1) * 64 + orow0) * 256 + hcol;
#pragma unroll
      for (int r = 0; r < 4; ++r)
        pnext[r] = pq[base + (size_t)r * 256];
    }

    __syncthreads();

    const unsigned short* hb = hl[t & 1];
    floatx4 acc[4] = {{0.f,0.f,0.f,0.f},{0.f,0.f,0.f,0.f},
                      {0.f,0.f,0.f,0.f},{0.f,0.f,0.f,0.f}};
#pragma unroll
    for (int kc = 0; kc < 8; ++kc) {
      short8_t av = *(const short8_t*)&hb[lh * 264 + kc * 32 + qd * 8];
#pragma unroll
      for (int g = 0; g < 4; ++g)
        acc[g] = __builtin_amdgcn_mfma_f32_16x16x32_bf16(av, wreg[g][kc], acc[g], 0, 0, 0);
    }

    float h[4];
#pragma unroll
    for (int r = 0; r < 4; ++r) {
      unsigned long long pv = pcur[r];
      float xf = acc[0][r] + bf2f((unsigned short)pv);
      float xi = acc[1][r] + bf2f((unsigned short)(pv >> 16));
      float xu = acc[2][r] + bf2f((unsigned short)(pv >> 32));
      float xo = acc[3][r] + bf2f((unsigned short)(pv >> 48));
      float fg = 1.0f / (1.0f + __expf(-xf));
      float ig = 1.0f / (1.0f + __expf(-xi));
      float gg = fast_tanh(xu);
      float og = 1.0f / (1.0f + __expf(-xo));
      float cc = fg * cst[r] + ig * gg;
      cst[r] = cc;
      h[r] = og * fast_tanh(cc);
    }

    float t0c, t1c, t2c, t3c;
    {
      float e0 = __shfl_xor(h[0], 1);
      float e1 = __shfl_xor(h[1], 1);
      float e2 = __shfl_xor(h[2], 1);
      float e3 = __shfl_xor(h[3], 1);
      bool odd = (lane & 1);
      float b0 = odd ? e1 : h[0];
      float b1 = odd ? h[1] : e0;
      float b2 = odd ? e3 : h[2];
      float b3 = odd ? h[3] : e2;
      float f0 = __shfl_xor(b0, 2);
      float f1 = __shfl_xor(b1, 2);
      float f2 = __shfl_xor(b2, 2);
      float f3 = __shfl_xor(b3, 2);
      bool hi = (lane & 2);
      t0c = hi ? f2 : b0;
      t1c = hi ? f3 : b1;
      t2c = hi ? b2 : f0;
      t3c = hi ? b3 : f1;
    }
    unsigned long long hp = (unsigned long long)f2bf(t0c)
        | ((unsigned long long)f2bf(t1c) << 16)
        | ((unsigned long long)f2bf(t2c) << 32)
        | ((unsigned long long)f2bf(t3c) << 48);
    const int orow = qd * 4 + (lane & 3);
    const int ocolq = w * 4 + (lh >> 2);

    __hip_atomic_store(&hxT[(size_t)((t * 4 + bg) * 4 + cg) * 256 + orow * 16 + ocolq],
                       hp, __ATOMIC_RELAXED, __HIP_MEMORY_SCOPE_AGENT);
    hlqW[orow * 66 + cg * 16 + ocolq] = hp;
    *(float4*)&out[(size_t)t * 16384 + (size_t)(bg * 16 + orow) * 256 + cg * 64 + ocolq * 4]
        = make_float4(t0c, t1c, t2c, t3c);

    if (t == 511) {
      const size_t hoff = (size_t)512 * 16384;
#pragma unroll
      for (int r = 0; r < 4; ++r) {
        out[hoff + (size_t)(orow0 + r) * 256 + hcol] = h[r];
        out[hoff + 16384 + (size_t)(orow0 + r) * 256 + hcol] = cst[r];
      }
    }
#pragma unroll
    for (int r = 0; r < 4; ++r) pcur[r] = pnext[r];
  }
}

// ---------------------------------------------------------------------------
extern "C" void kernel_launch(void* const* d_in, const int* in_sizes, int n_in,
                              void* d_out, int out_size, void* d_ws, size_t ws_size,
                              hipStream_t stream)
{
  const float* inputs = (const float*)d_in[0];
  const float* rot = (const float*)d_in[1];
  const float* ent = (const float*)d_in[2];
  const float* Wf = (const float*)d_in[3];
  const float* bf_ = (const float*)d_in[4];
  const float* Wi = (const float*)d_in[5];
  const float* bi_ = (const float*)d_in[6];
  const float* Wu = (const float*)d_in[7];
  const float* bu_ = (const float*)d_in[8];
  const float* Wo = (const float*)d_in[9];
  const float* bo_ = (const float*)d_in[10];
  const float* Wc = (const float*)d_in[11];
  const float* bc_ = (const float*)d_in[12];
  float* out = (float*)d_out;

  char* ws = (char*)d_ws;
  float* q  = (float*)(ws);                                   // 32 MiB [T,B,E]
  float* kb = (float*)(ws + (size_t)32 * 1024 * 1024);        // 32 MiB [T,B,E]
  float* S  = (float*)(ws + (size_t)64 * 1024 * 1024);        // 64 MiB [B,T,T]
  unsigned short* pre = (unsigned short*)S;                   // aliases S (dead)
  float* ctx = q;                                             // aliases q (dead)
  float* cp  = kb;                                            // aliases k (dead)
  // q region is dead after cp_kernel -> reuse for packed weights + hx timeline
  unsigned short* Wcat = (unsigned short*)ws;                 // 1 MiB [1024][512]
  float* bcat = (float*)(ws + (size_t)1048576);               // 4 KiB
  unsigned long long* hxT =
      (unsigned long long*)(ws + (size_t)2 * 1024 * 1024);    // 16 MiB [512][4][4][256]

  qk_kernel<<<dim3(4, 256), 256, 0, stream>>>(inputs, rot, ent, q, kb);
  scores_kernel<<<dim3(8, 8, 64), 256, 0, stream>>>(q, kb, S);
  softmax_kernel<<<dim3(32768), 256, 0, stream>>>(S);
  context_kernel<<<dim3(4, 8, 64), 256, 0, stream>>>(S, inputs, ctx);
  cp_kernel<<<dim3(4, 256), 256, 0, stream>>>(ctx, Wc, bc_, cp);
  // q region dead now: prefill hx timeline with 0xFF (bf16 NaN sentinel)
  hipMemsetAsync(hxT, 0xFF, (size_t)16 * 1024 * 1024, stream);
  pack_w<<<dim3(1024), 256, 0, stream>>>(Wf, Wi, Wu, Wo, bf_, bi_, bu_, bo_,
                                         Wcat, bcat);
  gemm_pre<<<dim3(16, 512), 256, 0, stream>>>(inputs, cp, Wcat, bcat, pre);
  scan_kernel<<<dim3(16), 256, 0, stream>>>(pre, Wcat, out, hxT);
}

// Round 14
// 1678.144 us; speedup vs baseline: 2.0600x; 1.0897x over previous
//
#include <hip/hip_runtime.h>

#define T_ 512
#define B_ 64
#define E_ 256
#define H_ 256

typedef __attribute__((ext_vector_type(8))) short short8_t;   // 8 bf16 (4 VGPRs)
typedef __attribute__((ext_vector_type(4))) float floatx4;

__device__ __forceinline__ unsigned short f2bf(float f) {
  unsigned int u = __float_as_uint(f);
  u += 0x7FFFu + ((u >> 16) & 1u);           // RTNE
  return (unsigned short)(u >> 16);
}
__device__ __forceinline__ float bf2f(unsigned short s) {
  return __uint_as_float(((unsigned int)s) << 16);
}
__device__ __forceinline__ float fast_tanh(float x) {
  // tanh(x) = 2/(1+e^{-2x}) - 1 ; exact at saturation, ~1e-7 abs err near 0
  float e = __expf(-2.0f * x);
  return 2.0f / (1.0f + e) - 1.0f;
}

// ---------------------------------------------------------------------------
// Kernel 1: fused q/k projection.  q[t,b,f] = sum_e inp[t,b,e] rot[e,f]
// M = T*B = 32768 flat rows, K=256, N=256.  fp32 (attention needs accuracy).
// ---------------------------------------------------------------------------
__global__ __launch_bounds__(256) void qk_kernel(
    const float* __restrict__ inp, const float* __restrict__ rot,
    const float* __restrict__ ent, float* __restrict__ qo, float* __restrict__ ko)
{
  __shared__ __align__(16) float As[16][136];
  __shared__ __align__(16) float B1[16][68];
  __shared__ __align__(16) float B2[16][68];
  const int tid = threadIdx.x;
  const int m0 = blockIdx.y * 128, n0 = blockIdx.x * 64;
  const int lk = tid & 15, lm = tid >> 4;
  const int ln = tid & 63, lkb = tid >> 6;
  const int tx = tid & 15, ty = tid >> 4;
  float acc1[8][4], acc2[8][4];
#pragma unroll
  for (int i = 0; i < 8; ++i)
#pragma unroll
    for (int j = 0; j < 4; ++j) { acc1[i][j] = 0.f; acc2[i][j] = 0.f; }

  for (int k0 = 0; k0 < 256; k0 += 16) {
    __syncthreads();
#pragma unroll
    for (int p = 0; p < 8; ++p) {
      int m = lm + p * 16;
      As[lk][m] = inp[(size_t)(m0 + m) * 256 + k0 + lk];
    }
#pragma unroll
    for (int p = 0; p < 4; ++p) {
      int kk = lkb + p * 4;
      B1[kk][ln] = rot[(size_t)(k0 + kk) * 256 + n0 + ln];
      B2[kk][ln] = ent[(size_t)(k0 + kk) * 256 + n0 + ln];
    }
    __syncthreads();
#pragma unroll
    for (int kk = 0; kk < 16; ++kk) {
      floatx4 a_lo = *(const floatx4*)&As[kk][ty * 8];
      floatx4 a_hi = *(const floatx4*)&As[kk][ty * 8 + 4];
      floatx4 b1v = *(const floatx4*)&B1[kk][tx * 4];
      floatx4 b2v = *(const floatx4*)&B2[kk][tx * 4];
#pragma unroll
      for (int i = 0; i < 4; ++i) {
        float alo = a_lo[i], ahi = a_hi[i];
#pragma unroll
        for (int j = 0; j < 4; ++j) {
          acc1[i][j]     += alo * b1v[j];
          acc1[i + 4][j] += ahi * b1v[j];
          acc2[i][j]     += alo * b2v[j];
          acc2[i + 4][j] += ahi * b2v[j];
        }
      }
    }
  }
#pragma unroll
  for (int i = 0; i < 8; ++i) {
    size_t row = (size_t)(m0 + ty * 8 + i);
    float4 v1 = make_float4(acc1[i][0], acc1[i][1], acc1[i][2], acc1[i][3]);
    float4 v2 = make_float4(acc2[i][0], acc2[i][1], acc2[i][2], acc2[i][3]);
    *(float4*)&qo[row * 256 + n0 + tx * 4] = v1;
    *(float4*)&ko[row * 256 + n0 + tx * 4] = v2;
  }
}

// ---------------------------------------------------------------------------
// Kernel 2: scores S[b,t,s] = (q[t,b,:] . k[s,b,:]) / 16   (NT, fp32)
// 128x128 tile, 8x8 acc/thread (VALU-bound; proven in round 10).
// ---------------------------------------------------------------------------
__global__ __launch_bounds__(256) void scores_kernel(
    const float* __restrict__ q, const float* __restrict__ k, float* __restrict__ S)
{
  __shared__ __align__(16) float As[16][136];
  __shared__ __align__(16) float Bs[16][136];
  const int tid = threadIdx.x;
  const int b = blockIdx.z;
  const int m0 = blockIdx.y * 128, n0 = blockIdx.x * 128;
  const int lk = tid & 15, lm = tid >> 4;
  const int tx = tid & 15, ty = tid >> 4;
  float acc[8][8];
#pragma unroll
  for (int i = 0; i < 8; ++i)
#pragma unroll
    for (int j = 0; j < 8; ++j) acc[i][j] = 0.f;

  const float* Ab = q + (size_t)b * 256;
  const float* Bb = k + (size_t)b * 256;
  for (int k0 = 0; k0 < 256; k0 += 16) {
    __syncthreads();
#pragma unroll
    for (int p = 0; p < 8; ++p) {
      int m = lm + p * 16;
      As[lk][m] = Ab[(size_t)(m0 + m) * 16384 + k0 + lk];
      Bs[lk][m] = Bb[(size_t)(n0 + m) * 16384 + k0 + lk];
    }
    __syncthreads();
#pragma unroll
    for (int kk = 0; kk < 16; ++kk) {
      floatx4 a_lo = *(const floatx4*)&As[kk][ty * 8];
      floatx4 a_hi = *(const floatx4*)&As[kk][ty * 8 + 4];
      floatx4 b_lo = *(const floatx4*)&Bs[kk][tx * 8];
      floatx4 b_hi = *(const floatx4*)&Bs[kk][tx * 8 + 4];
      float av[8], bv[8];
#pragma unroll
      for (int i = 0; i < 4; ++i) { av[i] = a_lo[i]; av[i + 4] = a_hi[i];
                                    bv[i] = b_lo[i]; bv[i + 4] = b_hi[i]; }
#pragma unroll
      for (int i = 0; i < 8; ++i)
#pragma unroll
        for (int j = 0; j < 8; ++j)
          acc[i][j] += av[i] * bv[j];
    }
  }
#pragma unroll
  for (int i = 0; i < 8; ++i) {
    size_t off = (size_t)b * 262144 + (size_t)(m0 + ty * 8 + i) * 512 + n0 + tx * 8;
    float4 v0 = make_float4(acc[i][0] * 0.0625f, acc[i][1] * 0.0625f,
                            acc[i][2] * 0.0625f, acc[i][3] * 0.0625f);
    float4 v1 = make_float4(acc[i][4] * 0.0625f, acc[i][5] * 0.0625f,
                            acc[i][6] * 0.0625f, acc[i][7] * 0.0625f);
    *(float4*)&S[off] = v0;
    *(float4*)&S[off + 4] = v1;
  }
}

// ---------------------------------------------------------------------------
// Kernel 3: in-place row softmax over 512 elements, 32768 rows.
// ---------------------------------------------------------------------------
__global__ __launch_bounds__(256) void softmax_kernel(float* __restrict__ S)
{
  float* p = S + (size_t)blockIdx.x * 512;
  const int tid = threadIdx.x;
  float x0 = p[tid], x1 = p[tid + 256];
  float m = fmaxf(x0, x1);
#pragma unroll
  for (int off = 32; off > 0; off >>= 1) m = fmaxf(m, __shfl_xor(m, off));
  __shared__ float red[8];
  const int wv = tid >> 6;
  if ((tid & 63) == 0) red[wv] = m;
  __syncthreads();
  m = fmaxf(fmaxf(red[0], red[1]), fmaxf(red[2], red[3]));
  float e0 = __expf(x0 - m);
  float e1 = __expf(x1 - m);
  float s = e0 + e1;
#pragma unroll
  for (int off = 32; off > 0; off >>= 1) s += __shfl_xor(s, off);
  if ((tid & 63) == 0) red[4 + wv] = s;
  __syncthreads();
  s = red[4] + red[5] + red[6] + red[7];
  float r = 1.0f / s;
  p[tid] = e0 * r;
  p[tid + 256] = e1 * r;
}

// ---------------------------------------------------------------------------
// Kernel 4: context[t,b,e] = sum_s P[b,t,s] * inp[s,b,e]   (NN, fp32)
// 128x128 tile, 8x8 acc/thread (proven in round 10).
// ---------------------------------------------------------------------------
__global__ __launch_bounds__(256) void context_kernel(
    const float* __restrict__ P, const float* __restrict__ inp, float* __restrict__ ctx)
{
  __shared__ __align__(16) float As[16][136];
  __shared__ __align__(16) float Bs[16][136];
  const int tid = threadIdx.x;
  const int b = blockIdx.z;
  const int m0 = blockIdx.y * 128, e0 = blockIdx.x * 128;
  const int lk = tid & 15, lm = tid >> 4;
  const int tx = tid & 15, ty = tid >> 4;
  const int bk = tid >> 7, be = tid & 127;   // B staging: 2 kk x 128 e per pass
  float acc[8][8];
#pragma unroll
  for (int i = 0; i < 8; ++i)
#pragma unroll
    for (int j = 0; j < 8; ++j) acc[i][j] = 0.f;

  const float* Ab = P + (size_t)b * 262144;
  for (int k0 = 0; k0 < 512; k0 += 16) {
    __syncthreads();
#pragma unroll
    for (int p = 0; p < 8; ++p) {
      int m = lm + p * 16;
      As[lk][m] = Ab[(size_t)(m0 + m) * 512 + k0 + lk];
    }
#pragma unroll
    for (int p = 0; p < 8; ++p) {
      int kk = bk + p * 2;
      Bs[kk][be] = inp[(size_t)(k0 + kk) * 16384 + b * 256 + e0 + be];
    }
    __syncthreads();
#pragma unroll
    for (int kk = 0; kk < 16; ++kk) {
      floatx4 a_lo = *(const floatx4*)&As[kk][ty * 8];
      floatx4 a_hi = *(const floatx4*)&As[kk][ty * 8 + 4];
      floatx4 b_lo = *(const floatx4*)&Bs[kk][tx * 8];
      floatx4 b_hi = *(const floatx4*)&Bs[kk][tx * 8 + 4];
      float av[8], bv[8];
#pragma unroll
      for (int i = 0; i < 4; ++i) { av[i] = a_lo[i]; av[i + 4] = a_hi[i];
                                    bv[i] = b_lo[i]; bv[i + 4] = b_hi[i]; }
#pragma unroll
      for (int i = 0; i < 8; ++i)
#pragma unroll
        for (int j = 0; j < 8; ++j)
          acc[i][j] += av[i] * bv[j];
    }
  }
#pragma unroll
  for (int i = 0; i < 8; ++i) {
    size_t off = (size_t)(m0 + ty * 8 + i) * 16384 + (size_t)b * 256 + e0 + tx * 8;
    float4 v0 = make_float4(acc[i][0], acc[i][1], acc[i][2], acc[i][3]);
    float4 v1 = make_float4(acc[i][4], acc[i][5], acc[i][6], acc[i][7]);
    *(float4*)&ctx[off] = v0;
    *(float4*)&ctx[off + 4] = v1;
  }
}

// ---------------------------------------------------------------------------
// Kernel 5a: pack gate weights transposed to bf16 (scan's Wh source).
// Wt[n][k], n = g*256+h: Wt[n*512+k] = W_g[k][h].  bcat[n] = b_g[h].
// ---------------------------------------------------------------------------
__global__ __launch_bounds__(256) void pack_w(
    const float* __restrict__ Wf, const float* __restrict__ Wi,
    const float* __restrict__ Wu, const float* __restrict__ Wo,
    const float* __restrict__ bfv, const float* __restrict__ biv,
    const float* __restrict__ buv, const float* __restrict__ bov,
    unsigned short* __restrict__ Wt, float* __restrict__ bcat)
{
  const int n = blockIdx.x;
  const int g = n >> 8, h = n & 255;
  const float* W = (g == 0) ? Wf : (g == 1) ? Wi : (g == 2) ? Wu : Wo;
  const float* bb = (g == 0) ? bfv : (g == 1) ? biv : (g == 2) ? buv : bov;
  for (int k = threadIdx.x; k < 512; k += 256)
    Wt[(size_t)n * 512 + k] = f2bf(W[(size_t)k * 256 + h]);
  if (threadIdx.x == 0) bcat[n] = bb[h];
}

// ---------------------------------------------------------------------------
// Kernel 5b: cp-FOLD.  pre's cp-half = (ctx@Wc + bc) @ Wh_slice
//   = ctx @ Wc2 + bias2, with Wc2[n][e] = sum_j Wc[e][j] W_g[256+j][h],
//     bias2[n] = b_g[h](n) + sum_j bc[j] W_g[256+j][h].
// Builds Wcat2[n][512]: cols 0..255 = bf16(W_g[k][h]) (x-part),
//                       cols 256..511 = bf16(Wc2[n][e]).
// One block per n; Wc (256 KB) is L2-resident across blocks.
// ---------------------------------------------------------------------------
__global__ __launch_bounds__(256) void fold_wc(
    const float* __restrict__ Wf, const float* __restrict__ Wi,
    const float* __restrict__ Wu, const float* __restrict__ Wo,
    const float* __restrict__ bfv, const float* __restrict__ biv,
    const float* __restrict__ buv, const float* __restrict__ bov,
    const float* __restrict__ Wc, const float* __restrict__ bc,
    unsigned short* __restrict__ Wt2, float* __restrict__ bcat2)
{
  const int n = blockIdx.x;
  const int g = n >> 8, h = n & 255;
  const float* W = (g == 0) ? Wf : (g == 1) ? Wi : (g == 2) ? Wu : Wo;
  const float* bb = (g == 0) ? bfv : (g == 1) ? biv : (g == 2) ? buv : bov;
  const int tid = threadIdx.x;
  __shared__ float wl[256];
  __shared__ float red[4];

  // x-part (k = tid)
  Wt2[(size_t)n * 512 + tid] = f2bf(W[(size_t)tid * 256 + h]);
  // stage recurrent column W_g[256+j][h]
  float wv = W[(size_t)(256 + tid) * 256 + h];
  wl[tid] = wv;
  __syncthreads();

  // fold column: e = tid
  float s = 0.f;
#pragma unroll 8
  for (int j = 0; j < 256; ++j)
    s += Wc[(size_t)tid * 256 + j] * wl[j];
  Wt2[(size_t)n * 512 + 256 + tid] = f2bf(s);

  // bias2 reduction: sum_j bc[j] * wl[j]
  float p = bc[tid] * wv;
#pragma unroll
  for (int off = 32; off > 0; off >>= 1) p += __shfl_xor(p, off);
  if ((tid & 63) == 0) red[tid >> 6] = p;
  __syncthreads();
  if (tid == 0) bcat2[n] = bb[h] + red[0] + red[1] + red[2] + red[3];
}

// ---------------------------------------------------------------------------
// Kernel 6: pre[m][n'] = bcat2[n] + sum_k A[m][k] Wt2[n][k]  via bf16 MFMA.
// A = [x | ctx] (fp32, converted in staging), M=32768, K=512, N=1024.
// 64x64 tile, 4 waves.  OUTPUT gate-interleaved n' = h*4 + g.
// ---------------------------------------------------------------------------
__global__ __launch_bounds__(256) void gemm_pre(
    const float* __restrict__ x, const float* __restrict__ ctx,
    const unsigned short* __restrict__ Wt2, const float* __restrict__ bcat2,
    unsigned short* __restrict__ pre)
{
  __shared__ __align__(16) unsigned short As[64 * 40];
  __shared__ __align__(16) unsigned short Bs[64 * 40];
  const int tid = threadIdx.x;
  const int n0 = blockIdx.x * 64, m0 = blockIdx.y * 64;
  const int lane = tid & 63, wv = tid >> 6;
  const int lm = lane & 15, qd = lane >> 4;
  const int sr = tid >> 2, sk = (tid & 3) * 8;
  floatx4 acc[4] = {{0.f,0.f,0.f,0.f},{0.f,0.f,0.f,0.f},
                    {0.f,0.f,0.f,0.f},{0.f,0.f,0.f,0.f}};
  for (int k0 = 0; k0 < 512; k0 += 32) {
    const float* Asrc = (k0 < 256)
        ? (x   + (size_t)(m0 + sr) * 256 + k0 + sk)
        : (ctx + (size_t)(m0 + sr) * 256 + (k0 - 256) + sk);
    float4 a0 = *(const float4*)Asrc;
    float4 a1 = *(const float4*)(Asrc + 4);
    short8_t av;
    av[0] = (short)f2bf(a0.x); av[1] = (short)f2bf(a0.y);
    av[2] = (short)f2bf(a0.z); av[3] = (short)f2bf(a0.w);
    av[4] = (short)f2bf(a1.x); av[5] = (short)f2bf(a1.y);
    av[6] = (short)f2bf(a1.z); av[7] = (short)f2bf(a1.w);
    short8_t bv = *(const short8_t*)&Wt2[(size_t)(n0 + sr) * 512 + k0 + sk];
    *(short8_t*)&As[sr * 40 + sk] = av;
    *(short8_t*)&Bs[sr * 40 + sk] = bv;
    __syncthreads();
    short8_t af = *(const short8_t*)&As[(wv * 16 + lm) * 40 + qd * 8];
#pragma unroll
    for (int nt = 0; nt < 4; ++nt) {
      short8_t bf = *(const short8_t*)&Bs[(nt * 16 + lm) * 40 + qd * 8];
      acc[nt] = __builtin_amdgcn_mfma_f32_16x16x32_bf16(af, bf, acc[nt], 0, 0, 0);
    }
    __syncthreads();
  }
#pragma unroll
  for (int nt = 0; nt < 4; ++nt) {
    int col = n0 + nt * 16 + lm;
    float bb = bcat2[col];
    int col2 = ((col & 255) << 2) | (col >> 8);   // gate-interleaved
#pragma unroll
    for (int r = 0; r < 4; ++r) {
      int row = m0 + wv * 16 + qd * 4 + r;
      pre[(size_t)row * 1024 + col2] = f2bf(acc[nt][r] + bb);
    }
  }
}

// ---------------------------------------------------------------------------
// Kernel 7: persistent LSTM scan — round-4 winner, VERBATIM (1092 us).
// 16 WGs = 4 batch-groups x 4 h-blocks.  Wh in VGPRs; write-once NaN-sentinel
// data-polled exchange; hl double-buffered; one barrier/step.
// ---------------------------------------------------------------------------
__global__ __launch_bounds__(256, 1) void scan_kernel(
    const unsigned short* __restrict__ pre,   // [32768][1024], col = h*4+g
    const unsigned short* __restrict__ Wt,    // [1024][512],  n = g*256+h
    float* __restrict__ out, unsigned long long* __restrict__ hxT)
{
  __shared__ __align__(16) unsigned short hl[2][16 * 264];  // h double-buffer
  const int tid = threadIdx.x;
  const int bg = blockIdx.x >> 2;      // batch group 0..3 (16 rows)
  const int cg = blockIdx.x & 3;       // h-block 0..3 (64 cols)
  const int lane = tid & 63;
  const int w = tid >> 6;              // wave 0..3 -> cols [w*16, w*16+16)
  const int qd = lane >> 4;
  const int lh = lane & 15;

  {
    unsigned long long* z = (unsigned long long*)hl;
    for (int i = tid; i < 2112; i += 256) z[i] = 0ull;
  }

  short8_t wreg[4][8];
#pragma unroll
  for (int g = 0; g < 4; ++g)
#pragma unroll
    for (int kc = 0; kc < 8; ++kc)
      wreg[g][kc] = *(const short8_t*)&Wt[(size_t)(g * 256 + cg * 64 + w * 16 + lh) * 512
                                          + 256 + kc * 32 + qd * 8];

  const unsigned long long* pq = (const unsigned long long*)pre;
  const int orow0 = bg * 16 + qd * 4;
  const int hcol = cg * 64 + w * 16 + lh;
  unsigned long long pcur[4], pnext[4];
#pragma unroll
  for (int r = 0; r < 4; ++r)
    pcur[r] = pq[(size_t)(orow0 + r) * 256 + hcol];

  float cst[4] = {0.f, 0.f, 0.f, 0.f};
  const int cg1 = (cg + 1) & 3, cg2 = (cg + 2) & 3, cg3 = (cg + 3) & 3;
  const int prow = tid >> 4, pcolq = tid & 15;

  __syncthreads();

#pragma unroll 1
  for (int t = 0; t < 512; ++t) {
    unsigned long long* hlqR = (unsigned long long*)hl[t & 1];
    unsigned long long* hlqW = (unsigned long long*)hl[(t + 1) & 1];

    if (t > 0) {
      const unsigned long long* sbase = hxT + (size_t)((t - 1) * 4 + bg) * 1024;
      const unsigned long long* s0 = sbase + (size_t)cg1 * 256;
      const unsigned long long* s1 = sbase + (size_t)cg2 * 256;
      const unsigned long long* s2 = sbase + (size_t)cg3 * 256;
      unsigned long long d0, d1, d2;
      bool ok;
      do {
        d0 = __hip_atomic_load(&s0[tid], __ATOMIC_RELAXED, __HIP_MEMORY_SCOPE_AGENT);
        d1 = __hip_atomic_load(&s1[tid], __ATOMIC_RELAXED, __HIP_MEMORY_SCOPE_AGENT);
        d2 = __hip_atomic_load(&s2[tid], __ATOMIC_RELAXED, __HIP_MEMORY_SCOPE_AGENT);
        ok = ((unsigned int)d0 != 0xFFFFFFFFu) && ((unsigned int)(d0 >> 32) != 0xFFFFFFFFu)
          && ((unsigned int)d1 != 0xFFFFFFFFu) && ((unsigned int)(d1 >> 32) != 0xFFFFFFFFu)
          && ((unsigned int)d2 != 0xFFFFFFFFu) && ((unsigned int)(d2 >> 32) != 0xFFFFFFFFu);
      } while (!__all((int)ok));
      hlqR[prow * 66 + cg1 * 16 + pcolq] = d0;
      hlqR[prow * 66 + cg2 * 16 + pcolq] = d1;
      hlqR[prow * 66 + cg3 * 16 + pcolq] = d2;
    }

    if (t < 511) {
      size_t base = (size_t)((t + 1) * 64 + orow0) * 256 + hcol;
#pragma unroll
      for (int r = 0; r < 4; ++r)
        pnext[r] = pq[base + (size_t)r * 256];
    }

    __syncthreads();

    const unsigned short* hb = hl[t & 1];
    floatx4 acc[4] = {{0.f,0.f,0.f,0.f},{0.f,0.f,0.f,0.f},
                      {0.f,0.f,0.f,0.f},{0.f,0.f,0.f,0.f}};
#pragma unroll
    for (int kc = 0; kc < 8; ++kc) {
      short8_t av = *(const short8_t*)&hb[lh * 264 + kc * 32 + qd * 8];
#pragma unroll
      for (int g = 0; g < 4; ++g)
        acc[g] = __builtin_amdgcn_mfma_f32_16x16x32_bf16(av, wreg[g][kc], acc[g], 0, 0, 0);
    }

    float h[4];
#pragma unroll
    for (int r = 0; r < 4; ++r) {
      unsigned long long pv = pcur[r];
      float xf = acc[0][r] + bf2f((unsigned short)pv);
      float xi = acc[1][r] + bf2f((unsigned short)(pv >> 16));
      float xu = acc[2][r] + bf2f((unsigned short)(pv >> 32));
      float xo = acc[3][r] + bf2f((unsigned short)(pv >> 48));
      float fg = 1.0f / (1.0f + __expf(-xf));
      float ig = 1.0f / (1.0f + __expf(-xi));
      float gg = fast_tanh(xu);
      float og = 1.0f / (1.0f + __expf(-xo));
      float cc = fg * cst[r] + ig * gg;
      cst[r] = cc;
      h[r] = og * fast_tanh(cc);
    }

    float t0c, t1c, t2c, t3c;
    {
      float e0 = __shfl_xor(h[0], 1);
      float e1 = __shfl_xor(h[1], 1);
      float e2 = __shfl_xor(h[2], 1);
      float e3 = __shfl_xor(h[3], 1);
      bool odd = (lane & 1);
      float b0 = odd ? e1 : h[0];
      float b1 = odd ? h[1] : e0;
      float b2 = odd ? e3 : h[2];
      float b3 = odd ? h[3] : e2;
      float f0 = __shfl_xor(b0, 2);
      float f1 = __shfl_xor(b1, 2);
      float f2 = __shfl_xor(b2, 2);
      float f3 = __shfl_xor(b3, 2);
      bool hi = (lane & 2);
      t0c = hi ? f2 : b0;
      t1c = hi ? f3 : b1;
      t2c = hi ? b2 : f0;
      t3c = hi ? b3 : f1;
    }
    unsigned long long hp = (unsigned long long)f2bf(t0c)
        | ((unsigned long long)f2bf(t1c) << 16)
        | ((unsigned long long)f2bf(t2c) << 32)
        | ((unsigned long long)f2bf(t3c) << 48);
    const int orow = qd * 4 + (lane & 3);
    const int ocolq = w * 4 + (lh >> 2);

    __hip_atomic_store(&hxT[(size_t)((t * 4 + bg) * 4 + cg) * 256 + orow * 16 + ocolq],
                       hp, __ATOMIC_RELAXED, __HIP_MEMORY_SCOPE_AGENT);
    hlqW[orow * 66 + cg * 16 + ocolq] = hp;
    *(float4*)&out[(size_t)t * 16384 + (size_t)(bg * 16 + orow) * 256 + cg * 64 + ocolq * 4]
        = make_float4(t0c, t1c, t2c, t3c);

    if (t == 511) {
      const size_t hoff = (size_t)512 * 16384;
#pragma unroll
      for (int r = 0; r < 4; ++r) {
        out[hoff + (size_t)(orow0 + r) * 256 + hcol] = h[r];
        out[hoff + 16384 + (size_t)(orow0 + r) * 256 + hcol] = cst[r];
      }
    }
#pragma unroll
    for (int r = 0; r < 4; ++r) pcur[r] = pnext[r];
  }
}

// ---------------------------------------------------------------------------
extern "C" void kernel_launch(void* const* d_in, const int* in_sizes, int n_in,
                              void* d_out, int out_size, void* d_ws, size_t ws_size,
                              hipStream_t stream)
{
  const float* inputs = (const float*)d_in[0];
  const float* rot = (const float*)d_in[1];
  const float* ent = (const float*)d_in[2];
  const float* Wf = (const float*)d_in[3];
  const float* bf_ = (const float*)d_in[4];
  const float* Wi = (const float*)d_in[5];
  const float* bi_ = (const float*)d_in[6];
  const float* Wu = (const float*)d_in[7];
  const float* bu_ = (const float*)d_in[8];
  const float* Wo = (const float*)d_in[9];
  const float* bo_ = (const float*)d_in[10];
  const float* Wc = (const float*)d_in[11];
  const float* bc_ = (const float*)d_in[12];
  float* out = (float*)d_out;

  char* ws = (char*)d_ws;
  float* q  = (float*)(ws);                                   // 32 MiB [T,B,E]; ctx aliases (q dead after scores)
  float* kb = (float*)(ws + (size_t)32 * 1024 * 1024);        // 32 MiB [T,B,E]; dead after scores
  float* S  = (float*)(ws + (size_t)64 * 1024 * 1024);        // 64 MiB [B,T,T]
  unsigned short* pre = (unsigned short*)S;                   // aliases S (dead after context)
  float* ctx = q;                                             // ctx lives until gemm_pre
  // kb region dead after scores -> packed weights + hx timeline live there
  unsigned short* Wcat  = (unsigned short*)(ws + (size_t)32 * 1024 * 1024);  // 1 MiB
  float* bcat           = (float*)(ws + (size_t)33 * 1024 * 1024);           // 4 KiB
  unsigned short* Wcat2 = (unsigned short*)(ws + (size_t)34 * 1024 * 1024);  // 1 MiB
  float* bcat2          = (float*)(ws + (size_t)35 * 1024 * 1024);           // 4 KiB
  unsigned long long* hxT =
      (unsigned long long*)(ws + (size_t)36 * 1024 * 1024);   // 16 MiB [512][4][4][256]

  qk_kernel<<<dim3(4, 256), 256, 0, stream>>>(inputs, rot, ent, q, kb);
  scores_kernel<<<dim3(4, 4, 64), 256, 0, stream>>>(q, kb, S);
  softmax_kernel<<<dim3(32768), 256, 0, stream>>>(S);
  context_kernel<<<dim3(2, 4, 64), 256, 0, stream>>>(S, inputs, ctx);
  // kb region dead now: build packed weights + prefill hx sentinel
  hipMemsetAsync(hxT, 0xFF, (size_t)16 * 1024 * 1024, stream);
  pack_w<<<dim3(1024), 256, 0, stream>>>(Wf, Wi, Wu, Wo, bf_, bi_, bu_, bo_,
                                         Wcat, bcat);
  fold_wc<<<dim3(1024), 256, 0, stream>>>(Wf, Wi, Wu, Wo, bf_, bi_, bu_, bo_,
                                          Wc, bc_, Wcat2, bcat2);
  gemm_pre<<<dim3(16, 512), 256, 0, stream>>>(inputs, ctx, Wcat2, bcat2, pre);
  scan_kernel<<<dim3(16), 256, 0, stream>>>(pre, Wcat, out, hxT);
}